// Round 1
// baseline (152.014 us; speedup 1.0000x reference)
//
#include <hip/hip_runtime.h>
#include <math.h>
#include <limits.h>

#define NB 128
#define NC 1000
#define NT 800

// ws layout: float maxl[NB]; float newconf[NB]; int jmin[NB];

__global__ void rowstats_kernel(const float* __restrict__ logits,
                                float* __restrict__ maxl,
                                float* __restrict__ newconf,
                                int* __restrict__ jmin) {
    int r = blockIdx.x;
    const float* row = logits + r * NC;
    __shared__ float red[256];
    int tid = threadIdx.x;

    // row max (exact: max of inputs, no rounding involved)
    float m = -INFINITY;
    for (int i = tid; i < NC; i += 256) m = fmaxf(m, row[i]);
    red[tid] = m;
    __syncthreads();
    for (int s = 128; s > 0; s >>= 1) {
        if (tid < s) red[tid] = fmaxf(red[tid], red[tid + s]);
        __syncthreads();
    }
    m = red[0];
    __syncthreads();

    // S = sum exp(l - m)  (order differs from np, margins vs bin edges are generous)
    float p = 0.f;
    for (int i = tid; i < NC; i += 256) p += expf(row[i] - m);
    red[tid] = p;
    __syncthreads();
    for (int s = 128; s > 0; s >>= 1) {
        if (tid < s) red[tid] += red[tid + s];
        __syncthreads();
    }

    if (tid == 0) {
        float S = red[0];
        float conf = 1.0f / S;   // max softmax prob = exp(0)/S

        const float third  = (float)(1.0 / 3.0);
        const float twoth  = (float)(2.0 / 3.0);
        const float nb0 = 0.8f;
        const float nb1 = (float)0.86666666666;
        const float nb2 = (float)0.93333333333;

        // replicate (uppers > conf) & (lowers <= conf), argmax with all-false -> 0
        bool b0 = (third > conf) && (0.0f  <= conf);
        bool b1 = (twoth > conf) && (third <= conf);
        bool b2 = (1.0f  > conf) && (twoth <= conf);
        int idx = b0 ? 0 : (b1 ? 1 : (b2 ? 2 : 0));

        float bl = (idx == 0) ? 0.0f : ((idx == 1) ? third : twoth);
        float nb = (idx == 0) ? nb0  : ((idx == 1) ? nb1   : nb2);

        const float TARGET = (float)0.2666666667;
        const float K      = (float)(1.0 / 15.0);
        float nc = nb + K * ((conf - bl) / TARGET);

        maxl[r] = m;
        newconf[r] = nc;
        jmin[r] = INT_MAX;
    }
}

__global__ __launch_bounds__(64) void sweep_kernel(const float* __restrict__ logits,
                                                   const float* __restrict__ maxl,
                                                   const float* __restrict__ newconf,
                                                   int* __restrict__ jmin) {
    int r = blockIdx.x;
    int j = blockIdx.y * 64 + threadIdx.x;

    __shared__ float4 sl[NC / 4];
    const float4* row4 = (const float4*)(logits + r * NC);
    for (int i = threadIdx.x; i < NC / 4; i += 64) sl[i] = row4[i];
    __syncthreads();

    if (j >= NT) return;

    float t  = 1.0f - 0.00125f * (float)j;   // matches temps[j] in f32
    float m2 = maxl[r] / t;                  // = max(scaled) exactly (monotone rounding)
    float S = 0.f;
    for (int i = 0; i < NC / 4; ++i) {
        float4 v = sl[i];
        // IEEE divide per element to match reference's logits/temp rounding
        S += expf(v.x / t - m2);
        S += expf(v.y / t - m2);
        S += expf(v.z / t - m2);
        S += expf(v.w / t - m2);
    }
    float lse   = m2 + logf(S);
    float conft = expf(m2 - lse);

    if (fabsf(conft - newconf[r]) <= 0.01f) atomicMin(&jmin[r], j);
}

__global__ void finalize_kernel(const float* __restrict__ logits,
                                const int* __restrict__ jmin,
                                float* __restrict__ out) {
    int g = blockIdx.x * 256 + threadIdx.x;
    if (g >= NB * NC) return;
    int r = g / NC;
    int j = jmin[r];
    float l = logits[g];
    if (j == INT_MAX) {
        out[g] = l;                          // not found -> identity
    } else {
        float t = 1.0f - 0.00125f * (float)j;
        out[g] = l / t;                      // IEEE divide, matches logits/chosen_temp
    }
}

extern "C" void kernel_launch(void* const* d_in, const int* in_sizes, int n_in,
                              void* d_out, int out_size, void* d_ws, size_t ws_size,
                              hipStream_t stream) {
    const float* logits = (const float*)d_in[0];
    float* out = (float*)d_out;

    float* maxl    = (float*)d_ws;
    float* newconf = maxl + NB;
    int*   jmin    = (int*)(newconf + NB);

    rowstats_kernel<<<NB, 256, 0, stream>>>(logits, maxl, newconf, jmin);

    dim3 grid(NB, (NT + 63) / 64);
    sweep_kernel<<<grid, 64, 0, stream>>>(logits, maxl, newconf, jmin);

    finalize_kernel<<<(NB * NC + 255) / 256, 256, 0, stream>>>(logits, jmin, out);
}

// Round 2
// 65.135 us; speedup vs baseline: 2.3338x; 2.3338x over previous
//
#include <hip/hip_runtime.h>
#include <math.h>

#define NB 128
#define NC 1000
#define NT 800

// Block-wide sum reduction over 256 threads (4 waves of 64).
// Protocol: wave shfl-xor reduce -> lane0 writes sred[wave] -> barrier ->
// tid0 combines + writes sbcast -> barrier -> all read. Exactly 2 barriers;
// safe for back-to-back reuse (sred writes of call k+1 can only happen after
// every thread has read sbcast of call k, because tid0's sbcast write in
// call k+1 sits behind call k+1's first barrier).
__device__ __forceinline__ float block_reduce_sum(float v, float* sred, float* sbcast) {
    for (int o = 32; o > 0; o >>= 1) v += __shfl_xor(v, o, 64);
    int tid = threadIdx.x;
    if ((tid & 63) == 0) sred[tid >> 6] = v;
    __syncthreads();
    if (tid == 0) *sbcast = (sred[0] + sred[1]) + (sred[2] + sred[3]);
    __syncthreads();
    return *sbcast;
}

// S(t) = sum_c exp(l_c/t - m/t) — identical per-element expression to the
// round-1 full-sweep kernel that passed (precise IEEE div + precise expf).
__device__ __forceinline__ float eval_S(const float* __restrict__ srow, float t, float m,
                                        float* sred, float* sbcast) {
    float m2 = m / t;
    float s = 0.f;
    for (int i = threadIdx.x; i < NC; i += 256)
        s += expf(srow[i] / t - m2);
    return block_reduce_sum(s, sred, sbcast);
}

__device__ __forceinline__ float conft_from_S(float S, float t, float m) {
    float m2 = t == 1.0f ? m : (m / t);
    float lse = m2 + logf(S);
    return expf(m2 - lse);
}

__global__ __launch_bounds__(256) void logitcomp_kernel(const float* __restrict__ logits,
                                                        float* __restrict__ out) {
    __shared__ float srow[NC];
    __shared__ float sred[4];
    __shared__ float sbcast;

    int r = blockIdx.x;
    int tid = threadIdx.x;
    const float* row = logits + r * NC;

    // stage row
    for (int i = tid; i < NC; i += 256) srow[i] = row[i];
    __syncthreads();

    // row max (exact)
    float mv = -INFINITY;
    for (int i = tid; i < NC; i += 256) mv = fmaxf(mv, srow[i]);
    for (int o = 32; o > 0; o >>= 1) mv = fmaxf(mv, __shfl_xor(mv, o, 64));
    if ((tid & 63) == 0) sred[tid >> 6] = mv;
    __syncthreads();
    if (tid == 0) sbcast = fmaxf(fmaxf(sred[0], sred[1]), fmaxf(sred[2], sred[3]));
    __syncthreads();
    float m = sbcast;

    // conf at t=1 (l/1.0f == l exactly, m/1.0f == m exactly)
    float S1 = eval_S(srow, 1.0f, m, sred, &sbcast);
    float conf = 1.0f / S1;

    // bin + new_conf (uniform, every thread computes redundantly)
    const float third = (float)(1.0 / 3.0);
    const float twoth = (float)(2.0 / 3.0);
    bool b0 = (third > conf) && (0.0f <= conf);
    bool b1 = (twoth > conf) && (third <= conf);
    bool b2 = (1.0f > conf) && (twoth <= conf);
    int idx = b0 ? 0 : (b1 ? 1 : (b2 ? 2 : 0));
    float bl = (idx == 0) ? 0.0f : ((idx == 1) ? third : twoth);
    float nb = (idx == 0) ? 0.8f : ((idx == 1) ? (float)0.86666666666 : (float)0.93333333333);
    const float TARGET = (float)0.2666666667;
    const float K = (float)(1.0 / 15.0);
    float nc = nb + K * ((conf - bl) / TARGET);

    // Binary search: conf_t(j) is monotone increasing in j. Find first j that
    // is NOT strictly below the band, where "below" reuses the exact reference
    // membership predicate so boundary membership is bit-consistent.
    int lo = 0, count = NT;
    while (count > 0) {
        int step = count >> 1;
        int mid = lo + step;
        float t = 1.0f - 0.00125f * (float)mid;     // temps[mid] in f32
        float S = eval_S(srow, t, m, sred, &sbcast);
        float conft = conft_from_S(S, t, m);
        bool ok = fabsf(conft - nc) <= 0.01f;
        bool below = (conft < nc) && !ok;
        if (below) { lo = mid + 1; count -= step + 1; }
        else        count = step;
    }

    // Verify membership at the found index with the reference predicate.
    bool found = false;
    float tch = 1.0f;
    if (lo < NT) {
        float t = 1.0f - 0.00125f * (float)lo;
        float S = eval_S(srow, t, m, sred, &sbcast);
        float conft = conft_from_S(S, t, m);
        found = fabsf(conft - nc) <= 0.01f;
        tch = t;
    }

    // write output (IEEE divide, matches logits/chosen_temp)
    float* orow = out + r * NC;
    for (int i = tid; i < NC; i += 256) {
        float l = srow[i];
        orow[i] = found ? (l / tch) : l;
    }
}

extern "C" void kernel_launch(void* const* d_in, const int* in_sizes, int n_in,
                              void* d_out, int out_size, void* d_ws, size_t ws_size,
                              hipStream_t stream) {
    const float* logits = (const float*)d_in[0];
    float* out = (float*)d_out;
    logitcomp_kernel<<<NB, 256, 0, stream>>>(logits, out);
}